// Round 2
// baseline (422.100 us; speedup 1.0000x reference)
//
#include <hip/hip_runtime.h>
#include <hip/hip_bf16.h>
#include <stdint.h>

// ---------------------------------------------------------------------------
// CausalSelfAttention on MI355X, round 2:
//   cast -> fused QKV GEMM (128x256 tile, BK=64, 3-buffer counted-vmcnt
//   pipeline, swizzled LDS, RoPE fused in epilogue) -> V transpose ->
//   flash attention (double-buffered KV, stage-ahead) -> out GEMM
// ---------------------------------------------------------------------------

typedef short bf16x8 __attribute__((ext_vector_type(8)));
typedef float f32x4  __attribute__((ext_vector_type(4)));

static __device__ __forceinline__ short f2bf(float f) {
  unsigned u = __builtin_bit_cast(unsigned, f);
  u = (u + 0x7fffu + ((u >> 16) & 1u)) >> 16;   // RNE
  return (short)u;
}
static __device__ __forceinline__ float bf2f(short s) {
  unsigned u = ((unsigned)(unsigned short)s) << 16;
  return __builtin_bit_cast(float, u);
}
static __device__ __forceinline__ void gload_lds16(const void* g, void* l) {
  auto gp = (const __attribute__((address_space(1))) void*)(g);
  auto lp = (__attribute__((address_space(3))) void*)(l);
  __builtin_amdgcn_global_load_lds(gp, lp, 16, 0, 0);
}
#define VMCNT(n) asm volatile("s_waitcnt vmcnt(" #n ")" ::: "memory")

// ------------------------------ cast kernels -------------------------------
__global__ __launch_bounds__(256) void cast8_kernel(const float* __restrict__ in,
                                                    short* __restrict__ out, int n8) {
  int g = blockIdx.x * 256 + threadIdx.x;
  if (g >= n8) return;
  const float4* p = (const float4*)(in + (size_t)g * 8);
  float4 a = p[0], b = p[1];
  bf16x8 o;
  o[0] = f2bf(a.x); o[1] = f2bf(a.y); o[2] = f2bf(a.z); o[3] = f2bf(a.w);
  o[4] = f2bf(b.x); o[5] = f2bf(b.y); o[6] = f2bf(b.z); o[7] = f2bf(b.w);
  *(bf16x8*)(out + (size_t)g * 8) = o;
}

__global__ __launch_bounds__(256) void castw_kernel(const float* __restrict__ w0,
                                                    const float* __restrict__ w1,
                                                    const float* __restrict__ w2,
                                                    const float* __restrict__ w3,
                                                    short* __restrict__ out) {
  int seg = blockIdx.y;
  const float* in = (seg == 0) ? w0 : (seg == 1) ? w1 : (seg == 2) ? w2 : w3;
  short* o = out + (size_t)seg * 4194304;
  int g = blockIdx.x * 256 + threadIdx.x;     // < 524288 exactly
  const float4* p = (const float4*)(in + (size_t)g * 8);
  float4 a = p[0], b = p[1];
  bf16x8 v;
  v[0] = f2bf(a.x); v[1] = f2bf(a.y); v[2] = f2bf(a.z); v[3] = f2bf(a.w);
  v[4] = f2bf(b.x); v[5] = f2bf(b.y); v[6] = f2bf(b.z); v[7] = f2bf(b.w);
  *(bf16x8*)(o + (size_t)g * 8) = v;
}

// ------------------------- V transpose (BHTD -> BHDT) ----------------------
__global__ __launch_bounds__(256) void transpose_v(const short* __restrict__ vb,
                                                   short* __restrict__ vt) {
  __shared__ char L[8192] __attribute__((aligned(128)));
  int bx = blockIdx.x;
  int bh = bx >> 6, rest = bx & 63, tt = rest >> 1, td = rest & 1;
  int t0 = tt * 64, d0 = td * 64;
  size_t base = (size_t)bh * (2048 * 128);
#pragma unroll
  for (int it = 0; it < 2; ++it) {
    int c = it * 256 + threadIdx.x;
    int t = c >> 3, dc = c & 7;
    bf16x8 v = *(const bf16x8*)(vb + base + (size_t)(t0 + t) * 128 + d0 + dc * 8);
#pragma unroll
    for (int i = 0; i < 8; ++i) {
      int d = dc * 8 + i;
      int g = (d & 7) ^ ((d >> 3) & 7);
      *(short*)(L + d * 128 + (((t >> 3) ^ g) * 16) + (t & 7) * 2) = v[i];
    }
  }
  __syncthreads();
#pragma unroll
  for (int it = 0; it < 2; ++it) {
    int c = it * 256 + threadIdx.x;
    int dr = c >> 3, tc = c & 7;
    int g = (dr & 7) ^ ((dr >> 3) & 7);
    bf16x8 v = *(const bf16x8*)(L + dr * 128 + ((tc ^ g) * 16));
    *(bf16x8*)(vt + base + (size_t)(d0 + dr) * 2048 + t0 + tc * 8) = v;
  }
}

// --------------------- GEMM: 128x256 tile, counted-vmcnt -------------------
// C = A(M x K) * W(N x K)^T, bf16 in. 512 threads = 8 waves (2M x 4N),
// per-wave 64x64 output (acc[4][4]). BK=64. 3 LDS buffers (A 16KB + B 32KB),
// stage-ahead-2 with s_waitcnt vmcnt(6) + raw s_barrier (never drains in loop).
// LDS XOR-swizzle: 16B-chunk index ^= (row&7), applied on the global source
// (linear LDS dest for global_load_lds) and on the ds_read address.
// MODE 0: fused QKV (NT=24) + RoPE fused in epilogue, writes bf16 (B,H,T,D).
// MODE 1: writes f32 row-major (final projection), NT=8.
template <int MODE>
__global__ __launch_bounds__(512, 1) void gemm8(const short* __restrict__ A,
                                                const short* __restrict__ W0,
                                                const short* __restrict__ W1,
                                                const short* __restrict__ W2,
                                                short* __restrict__ oq,
                                                short* __restrict__ ok_,
                                                short* __restrict__ ov,
                                                float* __restrict__ of,
                                                const float* __restrict__ fc,
                                                const float* __restrict__ fs,
                                                int NT) {
  const int SB = 49152;                        // bytes per LDS buffer
  __shared__ char lds[147456] __attribute__((aligned(128)));
  int nwg = gridDim.x;
  int bid = blockIdx.x;
  int wg = (bid & 7) * (nwg >> 3) + (bid >> 3);  // XCD-chunked (nwg%8==0)
  int mt = wg / NT, nt = wg % NT;
  const int tid = threadIdx.x;
  const int lane = tid & 63;
  const int wid = tid >> 6;
  const int wr = wid >> 2, wc = wid & 3;       // 2 x 4 waves
  const int l15 = lane & 15, l4 = lane >> 4;
  const short* Wp;
  int n0, wsel = 0;
  if (MODE == 0) {
    wsel = nt >> 3;
    Wp = (wsel == 0) ? W0 : ((wsel == 1) ? W1 : W2);
    n0 = (nt & 7) * 256;
  } else {
    Wp = W0;
    n0 = nt * 256;
  }
  const int m0 = mt * 128;
  const short* Ab = A + (size_t)m0 * 2048;
  const short* Wb = Wp + (size_t)n0 * 2048;

  const f32x4 vzero = {0.f, 0.f, 0.f, 0.f};
  f32x4 acc[4][4];
#pragma unroll
  for (int i = 0; i < 4; ++i)
#pragma unroll
    for (int j = 0; j < 4; ++j) acc[i][j] = vzero;

  // stage one K-tile (A: 128x64, B: 256x64) into buffer `b`
  auto stage = [&](int b, int t) {
    int k0 = t * 64;
    char* La = lds + b * SB;
    char* Lb = La + 16384;
#pragma unroll
    for (int j = 0; j < 2; ++j) {              // A: 1024 chunks of 16B
      int c = j * 512 + tid;
      int row = c >> 3, slot = c & 7;
      gload_lds16(Ab + (size_t)row * 2048 + k0 + ((slot ^ (row & 7)) * 8),
                  La + (c - lane) * 16);
    }
#pragma unroll
    for (int j = 0; j < 4; ++j) {              // B: 2048 chunks of 16B
      int c = j * 512 + tid;
      int row = c >> 3, slot = c & 7;
      gload_lds16(Wb + (size_t)row * 2048 + k0 + ((slot ^ (row & 7)) * 8),
                  Lb + (c - lane) * 16);
    }
  };

  stage(0, 0);
  stage(1, 1);
  VMCNT(6);                                    // buf0 landed (6 = buf1 loads)
  __builtin_amdgcn_s_barrier();

  int cb = 0, sb = 2;
#pragma unroll 1
  for (int t = 0; t < 32; ++t) {
    if (t + 2 < 32) stage(sb, t + 2);
    const char* La = lds + cb * SB;
    const char* Lb = La + 16384;
#pragma unroll
    for (int kk = 0; kk < 2; ++kk) {
      bf16x8 af[4], wf[4];
#pragma unroll
      for (int i = 0; i < 4; ++i) {
        int Ra = wr * 64 + i * 16 + l15;
        af[i] = *(const bf16x8*)(La + Ra * 128 + (((kk * 4 + l4) ^ (Ra & 7)) << 4));
        int Rb = wc * 64 + i * 16 + l15;
        wf[i] = *(const bf16x8*)(Lb + Rb * 128 + (((kk * 4 + l4) ^ (Rb & 7)) << 4));
      }
      __builtin_amdgcn_s_setprio(1);
#pragma unroll
      for (int mi = 0; mi < 4; ++mi)
#pragma unroll
        for (int ni = 0; ni < 4; ++ni)
          acc[mi][ni] = __builtin_amdgcn_mfma_f32_16x16x32_bf16(af[mi], wf[ni], acc[mi][ni], 0, 0, 0);
      __builtin_amdgcn_s_setprio(0);
    }
    if (t + 2 < 32) { VMCNT(6); } else { VMCNT(0); }
    __builtin_amdgcn_s_barrier();
    cb = (cb == 2) ? 0 : cb + 1;
    sb = (sb == 2) ? 0 : sb + 1;
  }

  // --------------------------- epilogue ---------------------------
  if (MODE == 0) {
    short* o = (wsel == 0) ? oq : ((wsel == 1) ? ok_ : ov);
#pragma unroll
    for (int mi = 0; mi < 4; ++mi) {
#pragma unroll
      for (int j = 0; j < 4; ++j) {
        int rr = m0 + wr * 64 + mi * 16 + l4 * 4 + j;
        int b = rr >> 11, t = rr & 2047;
#pragma unroll
        for (int ni = 0; ni < 4; ++ni) {
          int cc = n0 + wc * 64 + ni * 16 + l15;
          int h = cc >> 7, d = cc & 127;
          float v = acc[mi][ni][j];
          if (wsel < 2) {                       // RoPE on q,k (wave-uniform)
            float vp = __shfl_xor(v, 1);
            float c = fc[t * 64 + (d >> 1)];
            float s = fs[t * 64 + (d >> 1)];
            v = (lane & 1) ? (vp * s + v * c) : (v * c - vp * s);
            if (wsel == 0) v *= 0.08838834764831845f;  // 1/sqrt(128)
          }
          o[(((size_t)b * 16 + h) * 2048 + t) * 128 + d] = f2bf(v);
        }
      }
    }
  } else {
#pragma unroll
    for (int mi = 0; mi < 4; ++mi)
#pragma unroll
      for (int j = 0; j < 4; ++j) {
        int rr = m0 + wr * 64 + mi * 16 + l4 * 4 + j;
#pragma unroll
        for (int ni = 0; ni < 4; ++ni) {
          int cc = n0 + wc * 64 + ni * 16 + l15;
          of[(size_t)rr * 2048 + cc] = acc[mi][ni][j];
        }
      }
  }
}

// ------------------------------ flash attention ----------------------------
// 4 waves x 16 q-rows (BQ=64), KV tiles of 64, causal; block handles qtiles
// {p, 31-p}. Double-buffered K/Vt with stage-ahead-1: stage(kt+1) issued
// before compute(kt); single vmcnt(0)+barrier per iteration (overlaps HBM
// latency under QK^T+softmax+PV). Swizzled LDS as in round 1.
__global__ __launch_bounds__(256) void attn_kernel(const short* __restrict__ qb,
                                                   const short* __restrict__ kb,
                                                   const short* __restrict__ vt,
                                                   short* __restrict__ aout) {
  __shared__ char lds[73728] __attribute__((aligned(128)));
  // buffer b (b=0,1): K at b*32768 ([64][128] bf16), Vt at b*32768+16384
  // ([128][64] bf16); P at 65536 + w*2048.
  const int tid = threadIdx.x;
  const int lane = tid & 63;
  const int w = tid >> 6;
  const int l15 = lane & 15, l4 = lane >> 4;
  int bid0 = blockIdx.x;
  int bid = (bid0 & 7) * 64 + (bid0 >> 3);        // keep each bh on one XCD
  const int bh = bid >> 4, p = bid & 15;
  const size_t qkbase = (size_t)bh * (2048 * 128);
  char* Pb = lds + 65536 + w * 2048;
  const f32x4 vzero = {0.f, 0.f, 0.f, 0.f};

  auto stage = [&](int b, int kt) {
#pragma unroll
    for (int j = 0; j < 4; ++j) {
      int c = j * 256 + tid;                      // 0..1023
      int ldsoff = (c - lane) * 16;               // wave-uniform
      {
        int row = c >> 4, slot = c & 15;          // K: [64][128] bf16
        gload_lds16(kb + qkbase + (size_t)(kt * 64 + row) * 128 + ((slot ^ (row & 7)) * 8),
                    lds + b * 32768 + ldsoff);
      }
      {
        int row = c >> 3, slot = c & 7;           // Vt: [128][64] bf16
        gload_lds16(vt + qkbase + (size_t)row * 2048 + kt * 64 + ((slot ^ (row & 7)) * 8),
                    lds + b * 32768 + 16384 + ldsoff);
      }
    }
  };

#pragma unroll 1
  for (int half = 0; half < 2; ++half) {
    const int qtile = half ? (31 - p) : p;
    const int qbase = qtile << 6;
    const int qrow = qbase + w * 16 + l15;
    bf16x8 aq[4];
#pragma unroll
    for (int ks = 0; ks < 4; ++ks)
      aq[ks] = *(const bf16x8*)(qb + qkbase + (size_t)qrow * 128 + ks * 32 + l4 * 8);
    f32x4 accO[8];
#pragma unroll
    for (int nt = 0; nt < 8; ++nt) accO[nt] = vzero;
    float m_[4], l_[4];
#pragma unroll
    for (int j = 0; j < 4; ++j) { m_[j] = -1e30f; l_[j] = 0.f; }

    stage(0, 0);
    VMCNT(0);
    __builtin_amdgcn_s_barrier();

#pragma unroll 1
    for (int kt = 0; kt <= qtile; ++kt) {
      const int cbuf = kt & 1;
      if (kt < qtile) stage(cbuf ^ 1, kt + 1);
      const char* Kl = lds + cbuf * 32768;
      const char* Vl = Kl + 16384;

      // ---- S = Q K^T (q pre-scaled by 1/sqrt(D)) ----
      f32x4 s[4];
      __builtin_amdgcn_s_setprio(1);
#pragma unroll
      for (int ct = 0; ct < 4; ++ct) {
        s[ct] = vzero;
        int kcol = ct * 16 + l15;
#pragma unroll
        for (int ks = 0; ks < 4; ++ks) {
          bf16x8 bk = *(const bf16x8*)(Kl + kcol * 256 + ((ks * 64 + l4 * 16) ^ ((kcol & 7) << 4)));
          s[ct] = __builtin_amdgcn_mfma_f32_16x16x32_bf16(aq[ks], bk, s[ct], 0, 0, 0);
        }
      }
      __builtin_amdgcn_s_setprio(0);
      // ---- causal mask (only on the diagonal tile) ----
      if (kt * 64 + 63 > qbase + w * 16) {
#pragma unroll
        for (int ct = 0; ct < 4; ++ct) {
          int kc = kt * 64 + ct * 16 + l15;
#pragma unroll
          for (int j = 0; j < 4; ++j) {
            int r = qbase + w * 16 + l4 * 4 + j;
            if (kc > r) s[ct][j] = -1e30f;
          }
        }
      }
      // ---- online softmax (row groups of 16 lanes) ----
#pragma unroll
      for (int j = 0; j < 4; ++j) {
        float mx = fmaxf(fmaxf(s[0][j], s[1][j]), fmaxf(s[2][j], s[3][j]));
        mx = fmaxf(mx, __shfl_xor(mx, 1));
        mx = fmaxf(mx, __shfl_xor(mx, 2));
        mx = fmaxf(mx, __shfl_xor(mx, 4));
        mx = fmaxf(mx, __shfl_xor(mx, 8));
        float mn = fmaxf(m_[j], mx);
        float resc = __expf(m_[j] - mn);
        m_[j] = mn;
        float rs = 0.f;
#pragma unroll
        for (int ct = 0; ct < 4; ++ct) {
          float e = __expf(s[ct][j] - mn);
          s[ct][j] = e;
          rs += e;
        }
        rs += __shfl_xor(rs, 1);
        rs += __shfl_xor(rs, 2);
        rs += __shfl_xor(rs, 4);
        rs += __shfl_xor(rs, 8);
        l_[j] = l_[j] * resc + rs;
#pragma unroll
        for (int nt = 0; nt < 8; ++nt) accO[nt][j] *= resc;
      }
      // ---- P (C-layout) -> per-wave LDS (A-layout source), swizzled ----
#pragma unroll
      for (int ct = 0; ct < 4; ++ct)
#pragma unroll
        for (int j = 0; j < 4; ++j) {
          int r = l4 * 4 + j, cc = ct * 16 + l15;
          *(short*)(Pb + r * 128 + ((cc * 2) ^ ((r & 7) << 4))) = f2bf(s[ct][j]);
        }
      __threadfence_block();
      // ---- O += P V ----
      __builtin_amdgcn_s_setprio(1);
#pragma unroll
      for (int ks2 = 0; ks2 < 2; ++ks2) {
        bf16x8 pa = *(const bf16x8*)(Pb + l15 * 128 + ((ks2 * 64 + l4 * 16) ^ ((l15 & 7) << 4)));
#pragma unroll
        for (int nt = 0; nt < 8; ++nt) {
          int d = nt * 16 + l15;
          bf16x8 bv = *(const bf16x8*)(Vl + d * 128 + ((ks2 * 64 + l4 * 16) ^ ((d & 7) << 4)));
          accO[nt] = __builtin_amdgcn_mfma_f32_16x16x32_bf16(pa, bv, accO[nt], 0, 0, 0);
        }
      }
      __builtin_amdgcn_s_setprio(0);
      VMCNT(0);
      __builtin_amdgcn_s_barrier();
    }
    // ---- epilogue: normalize and write (B,T,C) bf16 ----
    const int b = bh >> 4, h = bh & 15;
#pragma unroll
    for (int j = 0; j < 4; ++j) {
      float inv = 1.0f / l_[j];
      int t = qbase + w * 16 + l4 * 4 + j;
      size_t obase = ((size_t)(b * 2048 + t)) * 2048 + h * 128;
#pragma unroll
      for (int nt = 0; nt < 8; ++nt)
        aout[obase + nt * 16 + l15] = f2bf(accO[nt][j] * inv);
    }
  }
}

// ------------------------------- launcher ----------------------------------
extern "C" void kernel_launch(void* const* d_in, const int* in_sizes, int n_in,
                              void* d_out, int out_size, void* d_ws, size_t ws_size,
                              hipStream_t stream) {
  const float* x  = (const float*)d_in[0];
  const float* fc = (const float*)d_in[1];
  const float* fs = (const float*)d_in[2];
  const float* wq = (const float*)d_in[3];
  const float* wk = (const float*)d_in[4];
  const float* wv = (const float*)d_in[5];
  const float* wo = (const float*)d_in[6];

  short* ws  = (short*)d_ws;
  short* xb  = ws;                    // x bf16; later reused as vt
  short* wqb = ws + 8388608;
  short* wkb = ws + 12582912;
  short* wvb = ws + 16777216;
  short* wob = ws + 20971520;
  short* qb  = ws + 25165824;         // (B,H,T,D) bf16
  short* kb  = ws + 33554432;
  short* vb  = ws + 41943040;         // later reused as aout
  short* vt  = xb;
  short* aout = vb;

  cast8_kernel<<<4096, 256, 0, stream>>>(x, xb, 1048576);
  castw_kernel<<<dim3(2048, 4), 256, 0, stream>>>(wq, wk, wv, wo, wqb);
  gemm8<0><<<768, 512, 0, stream>>>(xb, wqb, wkb, wvb, qb, kb, vb, nullptr, fc, fs, 24);
  transpose_v<<<2048, 256, 0, stream>>>(vb, vt);
  attn_kernel<<<512, 256, 0, stream>>>(qb, kb, vt, aout);
  gemm8<1><<<256, 512, 0, stream>>>(aout, wob, nullptr, nullptr,
                                    nullptr, nullptr, nullptr, (float*)d_out,
                                    nullptr, nullptr, 8);
}